// Round 9
// baseline (11069.547 us; speedup 1.0000x reference)
//
#include <hip/hip_runtime.h>
#include <hip/hip_fp16.h>
#include <math.h>

static constexpr int NB = 32;
static constexpr int NS = 8; // src slices (feat slice = N/NS * 384B ~= 2.4 MB, fits XCD L2)
static constexpr float CUTR = 5.0f;
static constexpr float SQRT3 = 1.7320508075688772f;
static constexpr float C2C = 2.7386127875258306f; // sqrt(7.5)

// feature record per node: 192 halves (384B)
// halves [0..63] sp ; [64+2h,65+2h] = (v0,v1) ; [128+h] = v2 ; rest pad
static constexpr int FSTR = 192;

union HU { unsigned u; __half2 h; };

__device__ inline unsigned pack2(float a, float b) {
    HU x;
    x.h = __halves2half2(__float2half_rn(a), __float2half_rn(b));
    return x.u;
}
__device__ inline float2 unpack2(unsigned u) {
    HU x; x.u = u;
    return __half22float2(x.h);
}

// ---------------- CSR build (keyed by dst*NS + src_slice) ----------------

__global__ void count_kernel(const int* __restrict__ ei, int* __restrict__ counts, int E, int N) {
    int e = blockIdx.x * blockDim.x + threadIdx.x;
    if (e < E) {
        int src = ei[e], dst = ei[E + e];
        int slice = (src * NS) / N;
        atomicAdd(&counts[dst * NS + slice], 1);
    }
}

__global__ __launch_bounds__(1024) void scan_kernel(const int* __restrict__ counts,
                                                    int* __restrict__ row_ptr,
                                                    int* __restrict__ cursor, int M) {
    __shared__ int part[1024];
    int t = threadIdx.x;
    int chunk = (M + 1023) >> 10;
    int beg = t * chunk, end = min(beg + chunk, M);
    int s = 0;
    for (int i = beg; i < end; ++i) s += counts[i];
    part[t] = s;
    __syncthreads();
    for (int off = 1; off < 1024; off <<= 1) {
        int v = (t >= off) ? part[t - off] : 0;
        __syncthreads();
        part[t] += v;
        __syncthreads();
    }
    int base = (t == 0) ? 0 : part[t - 1];
    for (int i = beg; i < end; ++i) {
        row_ptr[i] = base;
        cursor[i] = base;
        base += counts[i];
    }
    if (t == 1023) row_ptr[M] = part[1023];
}

// recG[e] = (src, d0, d1, d2)   16B
// recC[l*Epad + e] = (pack(a,b), pack(c2,q3), pack(q4,0), 0)   16B per layer
// records sorted by (dst, src_slice)
__global__ void build_kernel(const int* __restrict__ ei, const float* __restrict__ pos,
                             const float* __restrict__ shifts, const float* __restrict__ Wr,
                             const float* __restrict__ Wrb, int* __restrict__ cursor,
                             uint4* __restrict__ recG, uint4* __restrict__ recC,
                             int E, int Epad, int N) {
    int e = blockIdx.x * blockDim.x + threadIdx.x;
    if (e >= E) return;
    int src = ei[e], dst = ei[E + e];
    float ev0 = pos[dst * 3 + 0] - pos[src * 3 + 0] + shifts[e * 3 + 0];
    float ev1 = pos[dst * 3 + 1] - pos[src * 3 + 1] + shifts[e * 3 + 1];
    float ev2 = pos[dst * 3 + 2] - pos[src * 3 + 2] + shifts[e * 3 + 2];
    float r = sqrtf(ev0 * ev0 + ev1 * ev1 + ev2 * ev2);
    float rinv = 1.0f / fmaxf(r, 1e-8f);
    float d0 = ev0 * rinv, d1 = ev1 * rinv, d2 = ev2 * rinv;
    float u = r * (1.0f / CUTR);
    float gate = 0.0f;
    if (u < 1.0f) {
        float inner = 1.0f - u * u;
        gate = __expf(1.0f - 1.0f / inner);
    }
    float wacc[15];
#pragma unroll
    for (int k = 0; k < 15; ++k) wacc[k] = 0.0f;
    const float inv_w = (float)NB / CUTR;
    for (int b = 0; b < NB; ++b) {
        float t = (r - (float)b * (CUTR / (NB - 1))) * inv_w;
        float rb = __expf(-0.5f * t * t);
#pragma unroll
        for (int k = 0; k < 15; ++k)
            wacc[k] += rb * Wr[(k / 5) * (NB * 5) + b * 5 + (k % 5)];
    }
    int slice = (src * NS) / N;
    int p = atomicAdd(&cursor[dst * NS + slice], 1);
    recG[p] = make_uint4((unsigned)src, __float_as_uint(d0), __float_as_uint(d1), __float_as_uint(d2));
#pragma unroll
    for (int l = 0; l < 3; ++l) {
        float w0 = gate * wacc[l * 5 + 0] + Wrb[l * 5 + 0];
        float w1 = gate * wacc[l * 5 + 1] + Wrb[l * 5 + 1];
        float w2 = gate * wacc[l * 5 + 2] + Wrb[l * 5 + 2];
        float w3 = gate * wacc[l * 5 + 3] + Wrb[l * 5 + 3];
        float w4 = gate * wacc[l * 5 + 4] + Wrb[l * 5 + 4];
        float a  = gate * w0;
        float b  = gate * w1 * SQRT3;
        float c2 = gate * w2 * SQRT3;
        float q4 = gate * w4 * C2C;
        float q3 = gate * w3 - q4 * (1.0f / 3.0f);
        recC[(size_t)l * Epad + p] = make_uint4(pack2(a, b), pack2(c2, q3), pack2(q4, 0.0f), 0u);
    }
}

// ---------------- weight composition ----------------
__global__ void compose_kernel(const float* __restrict__ Ws, const float* __restrict__ Wv,
                               const float* __restrict__ Wos, const float* __restrict__ Wov,
                               float* __restrict__ Ms12, float* __restrict__ Mv12) {
    int t = blockIdx.x * blockDim.x + threadIdx.x;
    if (t < 2 * 4096) {
        int l = t >> 12;
        int idx = t & 4095;
        int j = idx >> 6, k = idx & 63;
        const float* A = Wos + l * 4096;
        const float* B = Ws + (l + 1) * 4096;
        float acc = 0.0f;
        for (int m = 0; m < 64; ++m) acc += A[j * 64 + m] * B[m * 64 + k];
        Ms12[t] = acc;
    } else if (t < 2 * 4096 + 2 * 1024) {
        int q = t - 2 * 4096;
        int l = q >> 10;
        int idx = q & 1023;
        int j = idx >> 5, k = idx & 31;
        const float* A = Wov + l * 1024;
        const float* B = Wv + (l + 1) * 1024;
        float acc = 0.0f;
        for (int m = 0; m < 32; ++m) acc += A[j * 32 + m] * B[m * 32 + k];
        Mv12[q] = acc;
    }
}

// ---------------- node transform (LDS-staged) ----------------
template <int MODE>
__global__ void node_transform(const float* __restrict__ s_in, const float* __restrict__ v_in,
                               const float* __restrict__ Ms, const float* __restrict__ Mv,
                               __half* __restrict__ feat, float* __restrict__ out160, int N) {
    __shared__ float sMs[64 * 64];
    __shared__ float sMv[32 * 32];
    __shared__ float sS[4][64];
    __shared__ float sV[4][3][32];
    for (int i = threadIdx.x; i < 4096; i += blockDim.x) sMs[i] = Ms[i];
    for (int i = threadIdx.x; i < 1024; i += blockDim.x) sMv[i] = Mv[i];
    int wid = threadIdx.x >> 6, lane = threadIdx.x & 63;
    int n = blockIdx.x * 4 + wid;
    bool act = n < N;
    int h = lane & 31;
    float asv = 0.f, av0 = 0.f, av1 = 0.f, av2 = 0.f;
    if (act) {
        asv = s_in[(size_t)n * 64 + lane];
        if (MODE == 0) {
            av0 = v_in[(size_t)n * 96 + h * 3 + 0];
            av1 = v_in[(size_t)n * 96 + h * 3 + 1];
            av2 = v_in[(size_t)n * 96 + h * 3 + 2];
        } else {
            av0 = v_in[(size_t)n * 32 + h];
            av1 = v_in[(size_t)N * 32 + (size_t)n * 32 + h];
            av2 = v_in[(size_t)2 * N * 32 + (size_t)n * 32 + h];
        }
    }
    sS[wid][lane] = asv;
    if (lane < 32) {
        sV[wid][0][h] = av0;
        sV[wid][1][h] = av1;
        sV[wid][2][h] = av2;
    }
    __syncthreads();
    if (!act) return;
    float acc = 0.0f;
#pragma unroll 8
    for (int i = 0; i < 64; ++i)
        acc += sS[wid][i] * sMs[i * 64 + lane];
    float vacc0 = 0.0f, vacc1 = 0.0f, vacc2 = 0.0f;
#pragma unroll 8
    for (int g = 0; g < 32; ++g) {
        float m = sMv[g * 32 + h];
        vacc0 += sV[wid][0][g] * m;
        vacc1 += sV[wid][1][g] * m;
        vacc2 += sV[wid][2][g] * m;
    }
    if (MODE == 2) {
        out160[(size_t)n * 160 + lane] = acc;
        if (lane < 32) {
            out160[(size_t)n * 160 + 64 + h * 3 + 0] = vacc0;
            out160[(size_t)n * 160 + 64 + h * 3 + 1] = vacc1;
            out160[(size_t)n * 160 + 64 + h * 3 + 2] = vacc2;
        }
    } else {
        feat[(size_t)n * FSTR + lane] = __float2half(acc);
        if (lane < 32) {
            *((__half2*)(feat + (size_t)n * FSTR + 64) + h) =
                __halves2half2(__float2half(vacc0), __float2half(vacc1));
            feat[(size_t)n * FSTR + 128 + h] = __float2half(vacc2);
        }
    }
}

// ---------------- edge aggregation: per src-slice pass, R7 ping-pong inner loop ----------------
// launch_bounds(256,4): proven config (64 VGPR, no spill). INIT pass writes, others RMW.
template <bool INIT>
__global__ __launch_bounds__(256, 4) void edge_agg(
        const uint4* __restrict__ recG, const uint4* __restrict__ recC,
        const int* __restrict__ row_ptr, const __half* __restrict__ feat,
        const float* __restrict__ Uvs_l, const float* __restrict__ Usv_l,
        float* __restrict__ as_out, float* __restrict__ avT_out, int N, int kpass) {
    __shared__ float sUvs[32 * 64];
    __shared__ float sUsv[64 * 32];
    for (int i = threadIdx.x; i < 2048; i += blockDim.x) {
        sUvs[i] = Uvs_l[i];
        sUsv[i] = Usv_l[i];
    }
    __syncthreads();
    int wid = threadIdx.x >> 6, lane = threadIdx.x & 63;
    int n = blockIdx.x * 4 + wid;
    if (n >= N) return;
    int beg = __builtin_amdgcn_readfirstlane(row_ptr[n * NS + kpass]);
    int end = __builtin_amdgcn_readfirstlane(row_ptr[n * NS + kpass + 1]);
    bool lo = lane < 32;
    int h = lane & 31;

    // prefetch previous partial (in flight across the edge loop)
    float oldS = 0.f, oldV0 = 0.f, oldV1 = 0.f, oldV2 = 0.f;
    if (!INIT) {
        oldS = as_out[(size_t)n * 64 + lane];
        if (lo) {
            oldV0 = avT_out[(size_t)n * 32 + h];
            oldV1 = avT_out[(size_t)N * 32 + (size_t)n * 32 + h];
            oldV2 = avT_out[(size_t)2 * N * 32 + (size_t)n * 32 + h];
        }
    }

    float S0 = 0.f, T10 = 0.f, T11 = 0.f, T12 = 0.f;
    float A1 = 0.f, V0 = 0.f, V1 = 0.f, V2 = 0.f;

#define DECLSET(S) \
    float S##d0[4], S##d1[4], S##d2[4]; \
    unsigned S##c0[4], S##c1[4], S##c2[4]; \
    __half S##sp[4]; __half2 S##v01[4]; __half S##v2[4];
    DECLSET(A)
    DECLSET(B)

#define LOADG(S, base) do { \
    int ib_ = __builtin_amdgcn_readfirstlane(base); \
    const uint4* Gp_ = recG + ib_; \
    const uint4* Cp_ = recC + ib_; \
    _Pragma("unroll") \
    for (int j_ = 0; j_ < 4; ++j_) { \
        uint4 g_ = Gp_[j_]; \
        uint4 c_ = Cp_[j_]; \
        bool val_ = (base + j_) < end; \
        S##d0[j_] = __uint_as_float(g_.y); \
        S##d1[j_] = __uint_as_float(g_.z); \
        S##d2[j_] = __uint_as_float(g_.w); \
        S##c0[j_] = val_ ? c_.x : 0u; \
        S##c1[j_] = val_ ? c_.y : 0u; \
        S##c2[j_] = val_ ? c_.z : 0u; \
        int sv_ = (int)min(g_.x, (unsigned)(N - 1)); \
        const __half* fb_ = feat + (size_t)sv_ * FSTR; \
        S##sp[j_] = fb_[lane]; \
        if (lo) { \
            S##v01[j_] = *(const __half2*)(fb_ + 64 + 2 * h); \
            S##v2[j_]  = fb_[128 + h]; \
        } \
    } \
} while (0)

#define ACCUM(S) do { \
    _Pragma("unroll") \
    for (int j_ = 0; j_ < 4; ++j_) { \
        float2 f0_ = unpack2(S##c0[j_]); \
        float2 f1_ = unpack2(S##c1[j_]); \
        float2 f2_ = unpack2(S##c2[j_]); \
        float spc_ = __half2float(S##sp[j_]); \
        S0  += f0_.x * spc_; \
        T10 += (f1_.x * S##d0[j_]) * spc_; \
        T11 += (f1_.x * S##d1[j_]) * spc_; \
        T12 += (f1_.x * S##d2[j_]) * spc_; \
        if (lo) { \
            float2 v01_ = __half22float2(S##v01[j_]); \
            float v2_ = __half2float(S##v2[j_]); \
            float pdot_ = S##d0[j_] * v01_.x + S##d1[j_] * v01_.y + S##d2[j_] * v2_; \
            A1 += f0_.y * pdot_; \
            float qp_ = f2_.x * pdot_; \
            V0 += f1_.y * v01_.x + qp_ * S##d0[j_]; \
            V1 += f1_.y * v01_.y + qp_ * S##d1[j_]; \
            V2 += f1_.y * v2_ + qp_ * S##d2[j_]; \
        } \
    } \
} while (0)

    if (beg < end) {
        int i = beg;
        LOADG(A, i);
        i += 4;
        int pend = 0;
        while (i < end) {
            if (pend == 0) { LOADG(B, i); ACCUM(A); pend = 1; }
            else           { LOADG(A, i); ACCUM(B); pend = 0; }
            i += 4;
        }
        if (pend == 0) ACCUM(A); else ACCUM(B);
    }

#undef LOADG
#undef ACCUM
#undef DECLSET

    // partial agg_s[c] = S0 + sum_h A1[h] * Uvs[h,c]   (linear fold per pass)
    float aggs = S0;
    for (int h2 = 0; h2 < 32; ++h2)
        aggs += __shfl(A1, h2) * sUvs[h2 * 64 + lane];
    as_out[(size_t)n * 64 + lane] = oldS + aggs;
    // partial agg_v[h,d] = V[h,d] + sum_c T1[c,d] * Usv[c,h]
    float av0 = V0, av1 = V1, av2 = V2;
    for (int c = 0; c < 64; ++c) {
        float uu = sUsv[c * 32 + h];
        av0 += __shfl(T10, c) * uu;
        av1 += __shfl(T11, c) * uu;
        av2 += __shfl(T12, c) * uu;
    }
    if (lo) {
        avT_out[(size_t)n * 32 + h] = oldV0 + av0;
        avT_out[(size_t)N * 32 + (size_t)n * 32 + h] = oldV1 + av1;
        avT_out[(size_t)2 * N * 32 + (size_t)n * 32 + h] = oldV2 + av2;
    }
}

// ---------------- host ----------------

extern "C" void kernel_launch(void* const* d_in, const int* in_sizes, int n_in,
                              void* d_out, int out_size, void* d_ws, size_t ws_size,
                              hipStream_t stream) {
    const float* pos    = (const float*)d_in[0];
    const float* sfeat  = (const float*)d_in[1];
    const float* vfeat  = (const float*)d_in[2];
    const float* shifts = (const float*)d_in[3];
    const int*   ei     = (const int*)d_in[4];
    const float* Ws     = (const float*)d_in[5];
    const float* Wv     = (const float*)d_in[6];
    const float* Uvs    = (const float*)d_in[7];
    const float* Usv    = (const float*)d_in[8];
    const float* Wr     = (const float*)d_in[9];
    const float* Wrb    = (const float*)d_in[10];
    const float* Wos    = (const float*)d_in[11];
    const float* Wov    = (const float*)d_in[12];
    float* out = (float*)d_out;

    const int N = in_sizes[0] / 3;
    const int E = in_sizes[4] / 2;
    const int Epad = E + 4;
    const int M = N * NS;

    char* w = (char*)d_ws;
    auto alloc = [&](size_t bytes) {
        char* p = w;
        w += (bytes + 255) & ~(size_t)255;
        return p;
    };
    int* counts     = (int*)alloc((size_t)M * 4);
    int* row_ptr    = (int*)alloc((size_t)(M + 1) * 4);
    int* cursor     = (int*)alloc((size_t)M * 4);
    float* Ms12     = (float*)alloc(2 * 4096 * 4);
    float* Mv12     = (float*)alloc(2 * 1024 * 4);
    __half* feat    = (__half*)alloc((size_t)N * FSTR * 2);
    float* asB      = (float*)alloc((size_t)N * 64 * 4);
    float* avB      = (float*)alloc((size_t)N * 32 * 3 * 4);
    uint4* recG     = (uint4*)alloc((size_t)Epad * 16);
    uint4* recC     = (uint4*)alloc((size_t)3 * Epad * 16);

    hipMemsetAsync(counts, 0, (size_t)M * 4, stream);

    int eb = (E + 255) / 256;
    count_kernel<<<eb, 256, 0, stream>>>(ei, counts, E, N);
    scan_kernel<<<1, 1024, 0, stream>>>(counts, row_ptr, cursor, M);
    build_kernel<<<eb, 256, 0, stream>>>(ei, pos, shifts, Wr, Wrb, cursor, recG, recC, E, Epad, N);
    compose_kernel<<<40, 256, 0, stream>>>(Ws, Wv, Wos, Wov, Ms12, Mv12);

    int nb = (N + 3) / 4;

    for (int l = 0; l < 3; ++l) {
        if (l == 0)
            node_transform<0><<<nb, 256, 0, stream>>>(sfeat, vfeat, Ws, Wv, feat, nullptr, N);
        else
            node_transform<1><<<nb, 256, 0, stream>>>(asB, avB, Ms12 + (size_t)(l - 1) * 4096,
                                                      Mv12 + (size_t)(l - 1) * 1024, feat, nullptr, N);
        const uint4* recCl = recC + (size_t)l * Epad;
        const float* Uvsl = Uvs + (size_t)l * 2048;
        const float* Usvl = Usv + (size_t)l * 2048;
        edge_agg<true><<<nb, 256, 0, stream>>>(recG, recCl, row_ptr, feat, Uvsl, Usvl, asB, avB, N, 0);
        for (int k = 1; k < NS; ++k)
            edge_agg<false><<<nb, 256, 0, stream>>>(recG, recCl, row_ptr, feat, Uvsl, Usvl, asB, avB, N, k);
    }
    // final output transform
    node_transform<2><<<nb, 256, 0, stream>>>(asB, avB, Wos + 2 * 4096, Wov + 2 * 1024, nullptr, out, N);
}

// Round 10
// 2493.313 us; speedup vs baseline: 4.4397x; 4.4397x over previous
//
#include <hip/hip_runtime.h>
#include <hip/hip_fp16.h>
#include <math.h>

static constexpr int NB = 32;
static constexpr int NS = 8;    // src slices: edge lists sorted by (dst, src_slice)
static constexpr int SCB = 256; // scan blocks
static constexpr float CUTR = 5.0f;
static constexpr float SQRT3 = 1.7320508075688772f;
static constexpr float C2C = 2.7386127875258306f; // sqrt(7.5)

// feature record per node: 192 halves (384B)
// halves [0..63] sp ; [64+2h,65+2h] = (v0,v1) ; [128+h] = v2 ; rest pad
static constexpr int FSTR = 192;

union HU { unsigned u; __half2 h; };

__device__ inline unsigned pack2(float a, float b) {
    HU x;
    x.h = __halves2half2(__float2half_rn(a), __float2half_rn(b));
    return x.u;
}
__device__ inline float2 unpack2(unsigned u) {
    HU x; x.u = u;
    return __half22float2(x.h);
}

// ---------------- CSR build (keyed by dst*NS + src_slice) ----------------

__global__ void count_kernel(const int* __restrict__ ei, int* __restrict__ counts, int E, int N) {
    int e = blockIdx.x * blockDim.x + threadIdx.x;
    if (e < E) {
        int src = ei[e], dst = ei[E + e];
        int slice = (int)(((long long)src * NS) / N);
        atomicAdd(&counts[dst * NS + slice], 1);
    }
}

// ---- multi-block scan over M elements: A (block sums) -> B (base scan) -> C (segmented scan)
__global__ __launch_bounds__(256) void scanA(const int* __restrict__ counts,
                                             int* __restrict__ partial, int M, int chunk) {
    __shared__ int red[256];
    int b = blockIdx.x, t = threadIdx.x;
    int beg = b * chunk, end = min(beg + chunk, M);
    int s = 0;
    for (int i = beg + t; i < end; i += 256) s += counts[i];
    red[t] = s;
    __syncthreads();
    for (int off = 128; off > 0; off >>= 1) {
        if (t < off) red[t] += red[t + off];
        __syncthreads();
    }
    if (t == 0) partial[b] = red[0];
}

__global__ __launch_bounds__(256) void scanB(int* __restrict__ partial) {
    __shared__ int sh[256];
    int t = threadIdx.x;
    sh[t] = partial[t];
    __syncthreads();
    for (int off = 1; off < 256; off <<= 1) {
        int v = (t >= off) ? sh[t - off] : 0;
        __syncthreads();
        sh[t] += v;
        __syncthreads();
    }
    partial[t] = t ? sh[t - 1] : 0; // exclusive base per block
}

__global__ __launch_bounds__(256) void scanC(const int* __restrict__ counts,
                                             const int* __restrict__ partial,
                                             int* __restrict__ rp2, int* __restrict__ cursor,
                                             int M, int chunk) {
    __shared__ int sh[256];
    __shared__ int carry;
    int b = blockIdx.x, t = threadIdx.x;
    int beg = b * chunk, end = min(beg + chunk, M);
    if (t == 0) carry = partial[b];
    __syncthreads();
    for (int s0 = beg; s0 < end; s0 += 256) {
        int i = s0 + t;
        int v = (i < end) ? counts[i] : 0;
        sh[t] = v;
        __syncthreads();
        for (int off = 1; off < 256; off <<= 1) {
            int u = (t >= off) ? sh[t - off] : 0;
            __syncthreads();
            sh[t] += u;
            __syncthreads();
        }
        if (i < end) {
            int ex = carry + sh[t] - v;
            rp2[i] = ex;
            cursor[i] = ex;
        }
        int tot = sh[255];
        __syncthreads();
        if (t == 0) carry += tot;
        __syncthreads();
    }
    if (b == gridDim.x - 1 && t == 0) rp2[M] = carry;
}

// recG[e] = (src, d0, d1, d2)   16B ; recC[l*Epad+e] = coeff fp16 pairs
// records sorted by (dst, src_slice) -> contiguous per dst, slice-ordered within
__global__ void build_kernel(const int* __restrict__ ei, const float* __restrict__ pos,
                             const float* __restrict__ shifts, const float* __restrict__ Wr,
                             const float* __restrict__ Wrb, int* __restrict__ cursor,
                             uint4* __restrict__ recG, uint4* __restrict__ recC,
                             int E, int Epad, int N) {
    int e = blockIdx.x * blockDim.x + threadIdx.x;
    if (e >= E) return;
    int src = ei[e], dst = ei[E + e];
    float ev0 = pos[dst * 3 + 0] - pos[src * 3 + 0] + shifts[e * 3 + 0];
    float ev1 = pos[dst * 3 + 1] - pos[src * 3 + 1] + shifts[e * 3 + 1];
    float ev2 = pos[dst * 3 + 2] - pos[src * 3 + 2] + shifts[e * 3 + 2];
    float r = sqrtf(ev0 * ev0 + ev1 * ev1 + ev2 * ev2);
    float rinv = 1.0f / fmaxf(r, 1e-8f);
    float d0 = ev0 * rinv, d1 = ev1 * rinv, d2 = ev2 * rinv;
    float u = r * (1.0f / CUTR);
    float gate = 0.0f;
    if (u < 1.0f) {
        float inner = 1.0f - u * u;
        gate = __expf(1.0f - 1.0f / inner);
    }
    float wacc[15];
#pragma unroll
    for (int k = 0; k < 15; ++k) wacc[k] = 0.0f;
    const float inv_w = (float)NB / CUTR;
    for (int b = 0; b < NB; ++b) {
        float t = (r - (float)b * (CUTR / (NB - 1))) * inv_w;
        float rb = __expf(-0.5f * t * t);
#pragma unroll
        for (int k = 0; k < 15; ++k)
            wacc[k] += rb * Wr[(k / 5) * (NB * 5) + b * 5 + (k % 5)];
    }
    int slice = (int)(((long long)src * NS) / N);
    int p = atomicAdd(&cursor[dst * NS + slice], 1);
    recG[p] = make_uint4((unsigned)src, __float_as_uint(d0), __float_as_uint(d1), __float_as_uint(d2));
#pragma unroll
    for (int l = 0; l < 3; ++l) {
        float w0 = gate * wacc[l * 5 + 0] + Wrb[l * 5 + 0];
        float w1 = gate * wacc[l * 5 + 1] + Wrb[l * 5 + 1];
        float w2 = gate * wacc[l * 5 + 2] + Wrb[l * 5 + 2];
        float w3 = gate * wacc[l * 5 + 3] + Wrb[l * 5 + 3];
        float w4 = gate * wacc[l * 5 + 4] + Wrb[l * 5 + 4];
        float a  = gate * w0;
        float b  = gate * w1 * SQRT3;
        float c2 = gate * w2 * SQRT3;
        float q4 = gate * w4 * C2C;
        float q3 = gate * w3 - q4 * (1.0f / 3.0f);
        recC[(size_t)l * Epad + p] = make_uint4(pack2(a, b), pack2(c2, q3), pack2(q4, 0.0f), 0u);
    }
}

// ---------------- weight composition ----------------
__global__ void compose_kernel(const float* __restrict__ Ws, const float* __restrict__ Wv,
                               const float* __restrict__ Wos, const float* __restrict__ Wov,
                               float* __restrict__ Ms12, float* __restrict__ Mv12) {
    int t = blockIdx.x * blockDim.x + threadIdx.x;
    if (t < 2 * 4096) {
        int l = t >> 12;
        int idx = t & 4095;
        int j = idx >> 6, k = idx & 63;
        const float* A = Wos + l * 4096;
        const float* B = Ws + (l + 1) * 4096;
        float acc = 0.0f;
        for (int m = 0; m < 64; ++m) acc += A[j * 64 + m] * B[m * 64 + k];
        Ms12[t] = acc;
    } else if (t < 2 * 4096 + 2 * 1024) {
        int q = t - 2 * 4096;
        int l = q >> 10;
        int idx = q & 1023;
        int j = idx >> 5, k = idx & 31;
        const float* A = Wov + l * 1024;
        const float* B = Wv + (l + 1) * 1024;
        float acc = 0.0f;
        for (int m = 0; m < 32; ++m) acc += A[j * 32 + m] * B[m * 32 + k];
        Mv12[q] = acc;
    }
}

// ---------------- node transform (LDS-staged) ----------------
template <int MODE>
__global__ void node_transform(const float* __restrict__ s_in, const float* __restrict__ v_in,
                               const float* __restrict__ Ms, const float* __restrict__ Mv,
                               __half* __restrict__ feat, float* __restrict__ out160, int N) {
    __shared__ float sMs[64 * 64];
    __shared__ float sMv[32 * 32];
    __shared__ float sS[4][64];
    __shared__ float sV[4][3][32];
    for (int i = threadIdx.x; i < 4096; i += blockDim.x) sMs[i] = Ms[i];
    for (int i = threadIdx.x; i < 1024; i += blockDim.x) sMv[i] = Mv[i];
    int wid = threadIdx.x >> 6, lane = threadIdx.x & 63;
    int n = blockIdx.x * 4 + wid;
    bool act = n < N;
    int h = lane & 31;
    float asv = 0.f, av0 = 0.f, av1 = 0.f, av2 = 0.f;
    if (act) {
        asv = s_in[(size_t)n * 64 + lane];
        if (MODE == 0) {
            av0 = v_in[(size_t)n * 96 + h * 3 + 0];
            av1 = v_in[(size_t)n * 96 + h * 3 + 1];
            av2 = v_in[(size_t)n * 96 + h * 3 + 2];
        } else {
            av0 = v_in[(size_t)n * 32 + h];
            av1 = v_in[(size_t)N * 32 + (size_t)n * 32 + h];
            av2 = v_in[(size_t)2 * N * 32 + (size_t)n * 32 + h];
        }
    }
    sS[wid][lane] = asv;
    if (lane < 32) {
        sV[wid][0][h] = av0;
        sV[wid][1][h] = av1;
        sV[wid][2][h] = av2;
    }
    __syncthreads();
    if (!act) return;
    float acc = 0.0f;
#pragma unroll 8
    for (int i = 0; i < 64; ++i)
        acc += sS[wid][i] * sMs[i * 64 + lane];
    float vacc0 = 0.0f, vacc1 = 0.0f, vacc2 = 0.0f;
#pragma unroll 8
    for (int g = 0; g < 32; ++g) {
        float m = sMv[g * 32 + h];
        vacc0 += sV[wid][0][g] * m;
        vacc1 += sV[wid][1][g] * m;
        vacc2 += sV[wid][2][g] * m;
    }
    if (MODE == 2) {
        out160[(size_t)n * 160 + lane] = acc;
        if (lane < 32) {
            out160[(size_t)n * 160 + 64 + h * 3 + 0] = vacc0;
            out160[(size_t)n * 160 + 64 + h * 3 + 1] = vacc1;
            out160[(size_t)n * 160 + 64 + h * 3 + 2] = vacc2;
        }
    } else {
        feat[(size_t)n * FSTR + lane] = __float2half(acc);
        if (lane < 32) {
            *((__half2*)(feat + (size_t)n * FSTR + 64) + h) =
                __halves2half2(__float2half(vacc0), __float2half(vacc1));
            feat[(size_t)n * FSTR + 128 + h] = __float2half(vacc2);
        }
    }
}

// ---------------- edge aggregation: R7 ping-pong walk over slice-sorted contiguous list ----------------
// launch_bounds(256,6): VGPR cap ~85 > 64 used -> no squeeze; 24 waves/CU vs 14 at (256,4)
__global__ __launch_bounds__(256, 6) void edge_agg(
        const uint4* __restrict__ recG, const uint4* __restrict__ recC,
        const int* __restrict__ rp2, const __half* __restrict__ feat,
        const float* __restrict__ Uvs_l, const float* __restrict__ Usv_l,
        float* __restrict__ as_out, float* __restrict__ avT_out, int N) {
    __shared__ float sUvs[32 * 64];
    __shared__ float sUsv[64 * 32];
    for (int i = threadIdx.x; i < 2048; i += blockDim.x) {
        sUvs[i] = Uvs_l[i];
        sUsv[i] = Usv_l[i];
    }
    __syncthreads();
    int wid = threadIdx.x >> 6, lane = threadIdx.x & 63;
    int n = blockIdx.x * 4 + wid;
    if (n >= N) return;
    int beg = __builtin_amdgcn_readfirstlane(rp2[n * NS]);
    int end = __builtin_amdgcn_readfirstlane(rp2[n * NS + NS]);
    bool lo = lane < 32;
    int h = lane & 31;

    float S0 = 0.f, T10 = 0.f, T11 = 0.f, T12 = 0.f;
    float A1 = 0.f, V0 = 0.f, V1 = 0.f, V2 = 0.f;

#define DECLSET(S) \
    float S##d0[4], S##d1[4], S##d2[4]; \
    unsigned S##c0[4], S##c1[4], S##c2[4]; \
    __half S##sp[4]; __half2 S##v01[4]; __half S##v2[4];
    DECLSET(A)
    DECLSET(B)

#define LOADG(S, base) do { \
    int ib_ = __builtin_amdgcn_readfirstlane(base); \
    const uint4* Gp_ = recG + ib_; \
    const uint4* Cp_ = recC + ib_; \
    _Pragma("unroll") \
    for (int j_ = 0; j_ < 4; ++j_) { \
        uint4 g_ = Gp_[j_]; \
        uint4 c_ = Cp_[j_]; \
        bool val_ = (base + j_) < end; \
        S##d0[j_] = __uint_as_float(g_.y); \
        S##d1[j_] = __uint_as_float(g_.z); \
        S##d2[j_] = __uint_as_float(g_.w); \
        S##c0[j_] = val_ ? c_.x : 0u; \
        S##c1[j_] = val_ ? c_.y : 0u; \
        S##c2[j_] = val_ ? c_.z : 0u; \
        int sv_ = (int)min(g_.x, (unsigned)(N - 1)); \
        const __half* fb_ = feat + (size_t)sv_ * FSTR; \
        S##sp[j_] = fb_[lane]; \
        if (lo) { \
            S##v01[j_] = *(const __half2*)(fb_ + 64 + 2 * h); \
            S##v2[j_]  = fb_[128 + h]; \
        } \
    } \
} while (0)

#define ACCUM(S) do { \
    _Pragma("unroll") \
    for (int j_ = 0; j_ < 4; ++j_) { \
        float2 f0_ = unpack2(S##c0[j_]); \
        float2 f1_ = unpack2(S##c1[j_]); \
        float2 f2_ = unpack2(S##c2[j_]); \
        float spc_ = __half2float(S##sp[j_]); \
        S0  += f0_.x * spc_; \
        T10 += (f1_.x * S##d0[j_]) * spc_; \
        T11 += (f1_.x * S##d1[j_]) * spc_; \
        T12 += (f1_.x * S##d2[j_]) * spc_; \
        if (lo) { \
            float2 v01_ = __half22float2(S##v01[j_]); \
            float v2_ = __half2float(S##v2[j_]); \
            float pdot_ = S##d0[j_] * v01_.x + S##d1[j_] * v01_.y + S##d2[j_] * v2_; \
            A1 += f0_.y * pdot_; \
            float qp_ = f2_.x * pdot_; \
            V0 += f1_.y * v01_.x + qp_ * S##d0[j_]; \
            V1 += f1_.y * v01_.y + qp_ * S##d1[j_]; \
            V2 += f1_.y * v2_ + qp_ * S##d2[j_]; \
        } \
    } \
} while (0)

    if (beg < end) {
        int i = beg;
        LOADG(A, i);
        i += 4;
        int pend = 0;
        while (i < end) {
            if (pend == 0) { LOADG(B, i); ACCUM(A); pend = 1; }
            else           { LOADG(A, i); ACCUM(B); pend = 0; }
            i += 4;
        }
        if (pend == 0) ACCUM(A); else ACCUM(B);
    }

#undef LOADG
#undef ACCUM
#undef DECLSET

    // agg_s[c] = S0 + sum_h A1[h] * Uvs[h,c]
    float aggs = S0;
    for (int h2 = 0; h2 < 32; ++h2)
        aggs += __shfl(A1, h2) * sUvs[h2 * 64 + lane];
    as_out[(size_t)n * 64 + lane] = aggs;
    // agg_v[h,d] = V[h,d] + sum_c T1[c,d] * Usv[c,h]
    float av0 = V0, av1 = V1, av2 = V2;
    for (int c = 0; c < 64; ++c) {
        float uu = sUsv[c * 32 + h];
        av0 += __shfl(T10, c) * uu;
        av1 += __shfl(T11, c) * uu;
        av2 += __shfl(T12, c) * uu;
    }
    if (lo) {
        avT_out[(size_t)n * 32 + h] = av0;
        avT_out[(size_t)N * 32 + (size_t)n * 32 + h] = av1;
        avT_out[(size_t)2 * N * 32 + (size_t)n * 32 + h] = av2;
    }
}

// ---------------- host ----------------

extern "C" void kernel_launch(void* const* d_in, const int* in_sizes, int n_in,
                              void* d_out, int out_size, void* d_ws, size_t ws_size,
                              hipStream_t stream) {
    const float* pos    = (const float*)d_in[0];
    const float* sfeat  = (const float*)d_in[1];
    const float* vfeat  = (const float*)d_in[2];
    const float* shifts = (const float*)d_in[3];
    const int*   ei     = (const int*)d_in[4];
    const float* Ws     = (const float*)d_in[5];
    const float* Wv     = (const float*)d_in[6];
    const float* Uvs    = (const float*)d_in[7];
    const float* Usv    = (const float*)d_in[8];
    const float* Wr     = (const float*)d_in[9];
    const float* Wrb    = (const float*)d_in[10];
    const float* Wos    = (const float*)d_in[11];
    const float* Wov    = (const float*)d_in[12];
    float* out = (float*)d_out;

    const int N = in_sizes[0] / 3;
    const int E = in_sizes[4] / 2;
    const int Epad = E + 4;
    const int M = N * NS;
    const int chunk = (M + SCB - 1) / SCB;

    char* w = (char*)d_ws;
    auto alloc = [&](size_t bytes) {
        char* p = w;
        w += (bytes + 255) & ~(size_t)255;
        return p;
    };
    int* counts     = (int*)alloc((size_t)M * 4);
    int* rp2        = (int*)alloc((size_t)(M + 1) * 4);
    int* cursor     = (int*)alloc((size_t)M * 4);
    int* partial    = (int*)alloc((size_t)SCB * 4);
    float* Ms12     = (float*)alloc(2 * 4096 * 4);
    float* Mv12     = (float*)alloc(2 * 1024 * 4);
    __half* feat    = (__half*)alloc((size_t)N * FSTR * 2);
    float* asB      = (float*)alloc((size_t)N * 64 * 4);
    float* avB      = (float*)alloc((size_t)N * 32 * 3 * 4);
    uint4* recG     = (uint4*)alloc((size_t)Epad * 16);
    uint4* recC     = (uint4*)alloc((size_t)3 * Epad * 16);

    hipMemsetAsync(counts, 0, (size_t)M * 4, stream);

    int eb = (E + 255) / 256;
    count_kernel<<<eb, 256, 0, stream>>>(ei, counts, E, N);
    scanA<<<SCB, 256, 0, stream>>>(counts, partial, M, chunk);
    scanB<<<1, 256, 0, stream>>>(partial);
    scanC<<<SCB, 256, 0, stream>>>(counts, partial, rp2, cursor, M, chunk);
    build_kernel<<<eb, 256, 0, stream>>>(ei, pos, shifts, Wr, Wrb, cursor, recG, recC, E, Epad, N);
    compose_kernel<<<40, 256, 0, stream>>>(Ws, Wv, Wos, Wov, Ms12, Mv12);

    int nb = (N + 3) / 4;

    // layer 0
    node_transform<0><<<nb, 256, 0, stream>>>(sfeat, vfeat, Ws, Wv, feat, nullptr, N);
    edge_agg<<<nb, 256, 0, stream>>>(recG, recC, rp2, feat, Uvs, Usv, asB, avB, N);
    // layer 1
    node_transform<1><<<nb, 256, 0, stream>>>(asB, avB, Ms12, Mv12, feat, nullptr, N);
    edge_agg<<<nb, 256, 0, stream>>>(recG, recC + (size_t)Epad, rp2, feat,
                                     Uvs + 2048, Usv + 2048, asB, avB, N);
    // layer 2
    node_transform<1><<<nb, 256, 0, stream>>>(asB, avB, Ms12 + 4096, Mv12 + 1024, feat, nullptr, N);
    edge_agg<<<nb, 256, 0, stream>>>(recG, recC + (size_t)2 * Epad, rp2, feat,
                                     Uvs + 4096, Usv + 4096, asB, avB, N);
    // final output transform
    node_transform<2><<<nb, 256, 0, stream>>>(asB, avB, Wos + 2 * 4096, Wov + 2 * 1024, nullptr, out, N);
}

// Round 12
// 1886.140 us; speedup vs baseline: 5.8689x; 1.3219x over previous
//
#include <hip/hip_runtime.h>
#include <hip/hip_fp16.h>
#include <math.h>

static constexpr int NB = 32;
static constexpr int NS = 8;    // src slices: edge lists sorted by (dst, src_slice)
static constexpr int SCB = 256; // scan blocks
static constexpr float CUTR = 5.0f;
static constexpr float SQRT3 = 1.7320508075688772f;
static constexpr float C2C = 2.7386127875258306f; // sqrt(7.5)

// feature record per node: 192 halves (384B)
// halves [0..63] sp ; [64+2h,65+2h] = (v0,v1) ; [128+h] = v2 ; rest pad
static constexpr int FSTR = 192;

union HU { unsigned u; __half2 h; };

__device__ inline unsigned pack2(float a, float b) {
    HU x;
    x.h = __halves2half2(__float2half_rn(a), __float2half_rn(b));
    return x.u;
}
__device__ inline float2 unpack2(unsigned u) {
    HU x; x.u = u;
    return __half22float2(x.h);
}

// ---------------- CSR build (keyed by dst*NS + src_slice) ----------------

__global__ void count_kernel(const int* __restrict__ ei, int* __restrict__ counts, int E, int N) {
    int e = blockIdx.x * blockDim.x + threadIdx.x;
    if (e < E) {
        int src = ei[e], dst = ei[E + e];
        int slice = (int)(((long long)src * NS) / N);
        atomicAdd(&counts[dst * NS + slice], 1);
    }
}

// ---- multi-block scan over M elements
__global__ __launch_bounds__(256) void scanA(const int* __restrict__ counts,
                                             int* __restrict__ partial, int M, int chunk) {
    __shared__ int red[256];
    int b = blockIdx.x, t = threadIdx.x;
    int beg = b * chunk, end = min(beg + chunk, M);
    int s = 0;
    for (int i = beg + t; i < end; i += 256) s += counts[i];
    red[t] = s;
    __syncthreads();
    for (int off = 128; off > 0; off >>= 1) {
        if (t < off) red[t] += red[t + off];
        __syncthreads();
    }
    if (t == 0) partial[b] = red[0];
}

__global__ __launch_bounds__(256) void scanB(int* __restrict__ partial) {
    __shared__ int sh[256];
    int t = threadIdx.x;
    sh[t] = partial[t];
    __syncthreads();
    for (int off = 1; off < 256; off <<= 1) {
        int v = (t >= off) ? sh[t - off] : 0;
        __syncthreads();
        sh[t] += v;
        __syncthreads();
    }
    partial[t] = t ? sh[t - 1] : 0; // exclusive base per block
}

__global__ __launch_bounds__(256) void scanC(const int* __restrict__ counts,
                                             const int* __restrict__ partial,
                                             int* __restrict__ rp2, int* __restrict__ cursor,
                                             int M, int chunk) {
    __shared__ int sh[256];
    __shared__ int carry;
    int b = blockIdx.x, t = threadIdx.x;
    int beg = b * chunk, end = min(beg + chunk, M);
    if (t == 0) carry = partial[b];
    __syncthreads();
    for (int s0 = beg; s0 < end; s0 += 256) {
        int i = s0 + t;
        int v = (i < end) ? counts[i] : 0;
        sh[t] = v;
        __syncthreads();
        for (int off = 1; off < 256; off <<= 1) {
            int u = (t >= off) ? sh[t - off] : 0;
            __syncthreads();
            sh[t] += u;
            __syncthreads();
        }
        if (i < end) {
            int ex = carry + sh[t] - v;
            rp2[i] = ex;
            cursor[i] = ex;
        }
        int tot = sh[255];
        __syncthreads();
        if (t == 0) carry += tot;
        __syncthreads();
    }
    if (b == gridDim.x - 1 && t == 0) rp2[M] = carry;
}

// recG[e] = (src, d0, d1, d2) 16B ; recC[l*Epad+e] = coeff fp16 pairs
__global__ void build_kernel(const int* __restrict__ ei, const float* __restrict__ pos,
                             const float* __restrict__ shifts, const float* __restrict__ Wr,
                             const float* __restrict__ Wrb, int* __restrict__ cursor,
                             uint4* __restrict__ recG, uint4* __restrict__ recC,
                             int E, int Epad, int N) {
    int e = blockIdx.x * blockDim.x + threadIdx.x;
    if (e >= E) return;
    int src = ei[e], dst = ei[E + e];
    float ev0 = pos[dst * 3 + 0] - pos[src * 3 + 0] + shifts[e * 3 + 0];
    float ev1 = pos[dst * 3 + 1] - pos[src * 3 + 1] + shifts[e * 3 + 1];
    float ev2 = pos[dst * 3 + 2] - pos[src * 3 + 2] + shifts[e * 3 + 2];
    float r = sqrtf(ev0 * ev0 + ev1 * ev1 + ev2 * ev2);
    float rinv = 1.0f / fmaxf(r, 1e-8f);
    float d0 = ev0 * rinv, d1 = ev1 * rinv, d2 = ev2 * rinv;
    float u = r * (1.0f / CUTR);
    float gate = 0.0f;
    if (u < 1.0f) {
        float inner = 1.0f - u * u;
        gate = __expf(1.0f - 1.0f / inner);
    }
    float wacc[15];
#pragma unroll
    for (int k = 0; k < 15; ++k) wacc[k] = 0.0f;
    const float inv_w = (float)NB / CUTR;
    for (int b = 0; b < NB; ++b) {
        float t = (r - (float)b * (CUTR / (NB - 1))) * inv_w;
        float rb = __expf(-0.5f * t * t);
#pragma unroll
        for (int k = 0; k < 15; ++k)
            wacc[k] += rb * Wr[(k / 5) * (NB * 5) + b * 5 + (k % 5)];
    }
    int slice = (int)(((long long)src * NS) / N);
    int p = atomicAdd(&cursor[dst * NS + slice], 1);
    recG[p] = make_uint4((unsigned)src, __float_as_uint(d0), __float_as_uint(d1), __float_as_uint(d2));
#pragma unroll
    for (int l = 0; l < 3; ++l) {
        float w0 = gate * wacc[l * 5 + 0] + Wrb[l * 5 + 0];
        float w1 = gate * wacc[l * 5 + 1] + Wrb[l * 5 + 1];
        float w2 = gate * wacc[l * 5 + 2] + Wrb[l * 5 + 2];
        float w3 = gate * wacc[l * 5 + 3] + Wrb[l * 5 + 3];
        float w4 = gate * wacc[l * 5 + 4] + Wrb[l * 5 + 4];
        float a  = gate * w0;
        float b  = gate * w1 * SQRT3;
        float c2 = gate * w2 * SQRT3;
        float q4 = gate * w4 * C2C;
        float q3 = gate * w3 - q4 * (1.0f / 3.0f);
        recC[(size_t)l * Epad + p] = make_uint4(pack2(a, b), pack2(c2, q3), pack2(q4, 0.0f), 0u);
    }
}

// ---------------- weight composition ----------------
__global__ void compose_kernel(const float* __restrict__ Ws, const float* __restrict__ Wv,
                               const float* __restrict__ Wos, const float* __restrict__ Wov,
                               float* __restrict__ Ms12, float* __restrict__ Mv12) {
    int t = blockIdx.x * blockDim.x + threadIdx.x;
    if (t < 2 * 4096) {
        int l = t >> 12;
        int idx = t & 4095;
        int j = idx >> 6, k = idx & 63;
        const float* A = Wos + l * 4096;
        const float* B = Ws + (l + 1) * 4096;
        float acc = 0.0f;
        for (int m = 0; m < 64; ++m) acc += A[j * 64 + m] * B[m * 64 + k];
        Ms12[t] = acc;
    } else if (t < 2 * 4096 + 2 * 1024) {
        int q = t - 2 * 4096;
        int l = q >> 10;
        int idx = q & 1023;
        int j = idx >> 5, k = idx & 31;
        const float* A = Wov + l * 1024;
        const float* B = Wv + (l + 1) * 1024;
        float acc = 0.0f;
        for (int m = 0; m < 32; ++m) acc += A[j * 32 + m] * B[m * 32 + k];
        Mv12[q] = acc;
    }
}

// ---------------- node transform (LDS-staged) ----------------
template <int MODE>
__global__ void node_transform(const float* __restrict__ s_in, const float* __restrict__ v_in,
                               const float* __restrict__ Ms, const float* __restrict__ Mv,
                               __half* __restrict__ feat, float* __restrict__ out160, int N) {
    __shared__ float sMs[64 * 64];
    __shared__ float sMv[32 * 32];
    __shared__ float sS[4][64];
    __shared__ float sV[4][3][32];
    for (int i = threadIdx.x; i < 4096; i += blockDim.x) sMs[i] = Ms[i];
    for (int i = threadIdx.x; i < 1024; i += blockDim.x) sMv[i] = Mv[i];
    int wid = threadIdx.x >> 6, lane = threadIdx.x & 63;
    int n = blockIdx.x * 4 + wid;
    bool act = n < N;
    int h = lane & 31;
    float asv = 0.f, av0 = 0.f, av1 = 0.f, av2 = 0.f;
    if (act) {
        asv = s_in[(size_t)n * 64 + lane];
        if (MODE == 0) {
            av0 = v_in[(size_t)n * 96 + h * 3 + 0];
            av1 = v_in[(size_t)n * 96 + h * 3 + 1];
            av2 = v_in[(size_t)n * 96 + h * 3 + 2];
        } else {
            av0 = v_in[(size_t)n * 32 + h];
            av1 = v_in[(size_t)N * 32 + (size_t)n * 32 + h];
            av2 = v_in[(size_t)2 * N * 32 + (size_t)n * 32 + h];
        }
    }
    sS[wid][lane] = asv;
    if (lane < 32) {
        sV[wid][0][h] = av0;
        sV[wid][1][h] = av1;
        sV[wid][2][h] = av2;
    }
    __syncthreads();
    if (!act) return;
    float acc = 0.0f;
#pragma unroll 8
    for (int i = 0; i < 64; ++i)
        acc += sS[wid][i] * sMs[i * 64 + lane];
    float vacc0 = 0.0f, vacc1 = 0.0f, vacc2 = 0.0f;
#pragma unroll 8
    for (int g = 0; g < 32; ++g) {
        float m = sMv[g * 32 + h];
        vacc0 += sV[wid][0][g] * m;
        vacc1 += sV[wid][1][g] * m;
        vacc2 += sV[wid][2][g] * m;
    }
    if (MODE == 2) {
        out160[(size_t)n * 160 + lane] = acc;
        if (lane < 32) {
            out160[(size_t)n * 160 + 64 + h * 3 + 0] = vacc0;
            out160[(size_t)n * 160 + 64 + h * 3 + 1] = vacc1;
            out160[(size_t)n * 160 + 64 + h * 3 + 2] = vacc2;
        }
    } else {
        feat[(size_t)n * FSTR + lane] = __float2half(acc);
        if (lane < 32) {
            *((__half2*)(feat + (size_t)n * FSTR + 64) + h) =
                __halves2half2(__float2half(vacc0), __float2half(vacc1));
            feat[(size_t)n * FSTR + 128 + h] = __float2half(vacc2);
        }
    }
}

// ---------------- edge aggregation: 3-deep ping-pong, slice-sorted contiguous walk ----------------
// (256,4): the only proven-safe bound (VGPR cap 128; kernel needs ~120)
__global__ __launch_bounds__(256, 4) void edge_agg(
        const uint4* __restrict__ recG, const uint4* __restrict__ recC,
        const int* __restrict__ rp2, const __half* __restrict__ feat,
        const float* __restrict__ Uvs_l, const float* __restrict__ Usv_l,
        float* __restrict__ as_out, float* __restrict__ avT_out, int N) {
    __shared__ float sUvs[32 * 64];
    __shared__ float sUsv[64 * 32];
    for (int i = threadIdx.x; i < 2048; i += blockDim.x) {
        sUvs[i] = Uvs_l[i];
        sUsv[i] = Usv_l[i];
    }
    __syncthreads();
    int wid = threadIdx.x >> 6, lane = threadIdx.x & 63;
    int n = blockIdx.x * 4 + wid;
    if (n >= N) return;
    int beg = __builtin_amdgcn_readfirstlane(rp2[n * NS]);
    int end = __builtin_amdgcn_readfirstlane(rp2[n * NS + NS]);
    bool lo = lane < 32;
    int h = lane & 31;

    float S0 = 0.f, T10 = 0.f, T11 = 0.f, T12 = 0.f;
    float A1 = 0.f, V0 = 0.f, V1 = 0.f, V2 = 0.f;

#define DECLSET(S) \
    float S##d0[4], S##d1[4], S##d2[4]; \
    unsigned S##c0[4], S##c1[4], S##c2[4]; \
    __half S##sp[4]; __half2 S##v01[4]; __half S##v2[4];
    DECLSET(A)
    DECLSET(B)
    DECLSET(C)

#define LOADG(S, base) do { \
    int ib_ = __builtin_amdgcn_readfirstlane(base); \
    const uint4* Gp_ = recG + ib_; \
    const uint4* Cp_ = recC + ib_; \
    _Pragma("unroll") \
    for (int j_ = 0; j_ < 4; ++j_) { \
        uint4 g_ = Gp_[j_]; \
        uint4 c_ = Cp_[j_]; \
        bool val_ = (base + j_) < end; \
        S##d0[j_] = __uint_as_float(g_.y); \
        S##d1[j_] = __uint_as_float(g_.z); \
        S##d2[j_] = __uint_as_float(g_.w); \
        S##c0[j_] = val_ ? c_.x : 0u; \
        S##c1[j_] = val_ ? c_.y : 0u; \
        S##c2[j_] = val_ ? c_.z : 0u; \
        int sv_ = (int)min(g_.x, (unsigned)(N - 1)); \
        const __half* fb_ = feat + (size_t)sv_ * FSTR; \
        S##sp[j_] = fb_[lane]; \
        if (lo) { \
            S##v01[j_] = *(const __half2*)(fb_ + 64 + 2 * h); \
            S##v2[j_]  = fb_[128 + h]; \
        } \
    } \
} while (0)

#define ACCUM(S) do { \
    _Pragma("unroll") \
    for (int j_ = 0; j_ < 4; ++j_) { \
        float2 f0_ = unpack2(S##c0[j_]); \
        float2 f1_ = unpack2(S##c1[j_]); \
        float2 f2_ = unpack2(S##c2[j_]); \
        float spc_ = __half2float(S##sp[j_]); \
        S0  += f0_.x * spc_; \
        T10 += (f1_.x * S##d0[j_]) * spc_; \
        T11 += (f1_.x * S##d1[j_]) * spc_; \
        T12 += (f1_.x * S##d2[j_]) * spc_; \
        if (lo) { \
            float2 v01_ = __half22float2(S##v01[j_]); \
            float v2_ = __half2float(S##v2[j_]); \
            float pdot_ = S##d0[j_] * v01_.x + S##d1[j_] * v01_.y + S##d2[j_] * v2_; \
            A1 += f0_.y * pdot_; \
            float qp_ = f2_.x * pdot_; \
            V0 += f1_.y * v01_.x + qp_ * S##d0[j_]; \
            V1 += f1_.y * v01_.y + qp_ * S##d1[j_]; \
            V2 += f1_.y * v2_ + qp_ * S##d2[j_]; \
        } \
    } \
} while (0)

    if (beg < end) {
        // 3-deep pipeline: 2 groups in flight ahead of each ACCUM
        LOADG(A, beg);
        LOADG(B, beg + 4);
        int i = beg + 8;
        int ph = 0;
        while (i < end) {
            if (ph == 0)      { LOADG(C, i); ACCUM(A); ph = 1; }
            else if (ph == 1) { LOADG(A, i); ACCUM(B); ph = 2; }
            else              { LOADG(B, i); ACCUM(C); ph = 0; }
            i += 4;
        }
        if (ph == 0)      { ACCUM(A); ACCUM(B); }
        else if (ph == 1) { ACCUM(B); ACCUM(C); }
        else              { ACCUM(C); ACCUM(A); }
    }

#undef LOADG
#undef ACCUM
#undef DECLSET

    // agg_s[c] = S0 + sum_h A1[h] * Uvs[h,c]
    float aggs = S0;
    for (int h2 = 0; h2 < 32; ++h2)
        aggs += __shfl(A1, h2) * sUvs[h2 * 64 + lane];
    as_out[(size_t)n * 64 + lane] = aggs;
    // agg_v[h,d] = V[h,d] + sum_c T1[c,d] * Usv[c,h]
    float av0 = V0, av1 = V1, av2 = V2;
    for (int c = 0; c < 64; ++c) {
        float uu = sUsv[c * 32 + h];
        av0 += __shfl(T10, c) * uu;
        av1 += __shfl(T11, c) * uu;
        av2 += __shfl(T12, c) * uu;
    }
    if (lo) {
        avT_out[(size_t)n * 32 + h] = av0;
        avT_out[(size_t)N * 32 + (size_t)n * 32 + h] = av1;
        avT_out[(size_t)2 * N * 32 + (size_t)n * 32 + h] = av2;
    }
}

// ---------------- host ----------------

extern "C" void kernel_launch(void* const* d_in, const int* in_sizes, int n_in,
                              void* d_out, int out_size, void* d_ws, size_t ws_size,
                              hipStream_t stream) {
    const float* pos    = (const float*)d_in[0];
    const float* sfeat  = (const float*)d_in[1];
    const float* vfeat  = (const float*)d_in[2];
    const float* shifts = (const float*)d_in[3];
    const int*   ei     = (const int*)d_in[4];
    const float* Ws     = (const float*)d_in[5];
    const float* Wv     = (const float*)d_in[6];
    const float* Uvs    = (const float*)d_in[7];
    const float* Usv    = (const float*)d_in[8];
    const float* Wr     = (const float*)d_in[9];
    const float* Wrb    = (const float*)d_in[10];
    const float* Wos    = (const float*)d_in[11];
    const float* Wov    = (const float*)d_in[12];
    float* out = (float*)d_out;

    const int N = in_sizes[0] / 3;
    const int E = in_sizes[4] / 2;
    const int Epad = E + 8;
    const int M = N * NS;
    const int chunk = (M + SCB - 1) / SCB;

    char* w = (char*)d_ws;
    auto alloc = [&](size_t bytes) {
        char* p = w;
        w += (bytes + 255) & ~(size_t)255;
        return p;
    };
    int* counts     = (int*)alloc((size_t)M * 4);
    int* rp2        = (int*)alloc((size_t)(M + 1) * 4);
    int* cursor     = (int*)alloc((size_t)M * 4);
    int* partial    = (int*)alloc((size_t)SCB * 4);
    float* Ms12     = (float*)alloc(2 * 4096 * 4);
    float* Mv12     = (float*)alloc(2 * 1024 * 4);
    __half* feat    = (__half*)alloc((size_t)N * FSTR * 2);
    float* asB      = (float*)alloc((size_t)N * 64 * 4);
    float* avB      = (float*)alloc((size_t)N * 32 * 3 * 4);
    uint4* recG     = (uint4*)alloc((size_t)Epad * 16);
    uint4* recC     = (uint4*)alloc((size_t)3 * Epad * 16);

    hipMemsetAsync(counts, 0, (size_t)M * 4, stream);

    int eb = (E + 255) / 256;
    count_kernel<<<eb, 256, 0, stream>>>(ei, counts, E, N);
    scanA<<<SCB, 256, 0, stream>>>(counts, partial, M, chunk);
    scanB<<<1, 256, 0, stream>>>(partial);
    scanC<<<SCB, 256, 0, stream>>>(counts, partial, rp2, cursor, M, chunk);
    build_kernel<<<eb, 256, 0, stream>>>(ei, pos, shifts, Wr, Wrb, cursor, recG, recC, E, Epad, N);
    compose_kernel<<<40, 256, 0, stream>>>(Ws, Wv, Wos, Wov, Ms12, Mv12);

    int nb = (N + 3) / 4;

    // layer 0
    node_transform<0><<<nb, 256, 0, stream>>>(sfeat, vfeat, Ws, Wv, feat, nullptr, N);
    edge_agg<<<nb, 256, 0, stream>>>(recG, recC, rp2, feat, Uvs, Usv, asB, avB, N);
    // layer 1
    node_transform<1><<<nb, 256, 0, stream>>>(asB, avB, Ms12, Mv12, feat, nullptr, N);
    edge_agg<<<nb, 256, 0, stream>>>(recG, recC + (size_t)Epad, rp2, feat,
                                     Uvs + 2048, Usv + 2048, asB, avB, N);
    // layer 2
    node_transform<1><<<nb, 256, 0, stream>>>(asB, avB, Ms12 + 4096, Mv12 + 1024, feat, nullptr, N);
    edge_agg<<<nb, 256, 0, stream>>>(recG, recC + (size_t)2 * Epad, rp2, feat,
                                     Uvs + 4096, Usv + 4096, asB, avB, N);
    // final output transform
    node_transform<2><<<nb, 256, 0, stream>>>(asB, avB, Wos + 2 * 4096, Wov + 2 * 1024, nullptr, out, N);
}